// Round 3
// baseline (122.631 us; speedup 1.0000x reference)
//
#include <hip/hip_runtime.h>

#define N_Q     40000
#define N_S     40000
#define KK      32
#define PP      15
#define IN_DIM  64
#define OUT_DIM 128
#define MAXH    32   // recorded hits per query (expected ~0.22, cap generous)

// ws layout (256 MiB available):
//   cnt     : N_Q ints        @ 0
//   valid   : N_S ints        @ 512 KiB
//   rec_key : N_Q*MAXH ints   @ 1  MiB   (id | p<<16; id<40000 fits 16 bits)
//   rec_w   : N_Q*MAXH floats @ 16 MiB   (weight / neighbor_num, pre-scaled)

// Kernel 1: valid[s] = (sum_d x[s,d] > 0), and zero the per-query hit counters
// (N_Q == N_S so one pass covers both). 16 lanes per row, coalesced float4.
__global__ __launch_bounds__(256) void rowsum_valid_kernel(
    const float* __restrict__ x, int* __restrict__ valid, int* __restrict__ cnt) {
  int t = blockIdx.x * 256 + threadIdx.x;
  int row = t >> 4;   // 16 lanes per row
  int sub = t & 15;
  if (row >= N_S) return;
  float4 v = reinterpret_cast<const float4*>(x + (size_t)row * IN_DIM)[sub];
  float s = (v.x + v.y) + (v.z + v.w);
  s += __shfl_xor(s, 1, 64);
  s += __shfl_xor(s, 2, 64);
  s += __shfl_xor(s, 4, 64);
  s += __shfl_xor(s, 8, 64);
  if (sub == 0) {
    valid[row] = (s > 0.0f) ? 1 : 0;
    cnt[row] = 0;
  }
}

// Kernel 2: one thread per (query, neighbor). Kernel points preloaded into
// registers ONCE (R1/R2 re-read them every p-iteration -> ~15 serialized
// global-load latencies per wave = the ~50 us plateau). Rare hits appended
// to per-query slot buffers; no matvec here.
__global__ __launch_bounds__(256) void detect_kernel(
    const float* __restrict__ q_pts, const float* __restrict__ s_pts,
    const int* __restrict__ nidx, const float* __restrict__ kpts,
    const int* __restrict__ valid, int* __restrict__ cnt,
    int* __restrict__ rec_key, float* __restrict__ rec_w) {
  const int tid  = blockIdx.x * 256 + threadIdx.x;
  const int lane = threadIdx.x & 63;
  const int n = tid >> 5;        // query index (2 per wave)

  // 45 uniform floats -> registers, one pipelined wait
  float kx[PP], ky[PP], kz[PP];
  #pragma unroll
  for (int p = 0; p < PP; ++p) {
    kx[p] = kpts[p * 3 + 0];
    ky[p] = kpts[p * 3 + 1];
    kz[p] = kpts[p * 3 + 2];
  }

  const int id = nidx[tid];      // coalesced
  const bool real = (id < N_S);  // id == N_S: shadow row at origin, zero feats
  float ox = 0.f, oy = 0.f, oz = 0.f;
  int v = 0;
  if (real) {
    ox = s_pts[id * 3 + 0];
    oy = s_pts[id * 3 + 1];
    oz = s_pts[id * 3 + 2];
    v  = valid[id];
  }
  ox -= q_pts[n * 3 + 0];
  oy -= q_pts[n * 3 + 1];
  oz -= q_pts[n * 3 + 2];

  // neighbor_num per query: popcount of my half-wave's ballot
  unsigned long long bal = __ballot(v != 0);
  unsigned int half = (lane < 32) ? (unsigned int)bal
                                  : (unsigned int)(bal >> 32);
  int num = (int)__popc(half);
  if (num < 1) num = 1;
  const float invnum = 1.0f / (float)num;

  if (!real) return;   // no cross-lane ops past this point

  #pragma unroll
  for (int p = 0; p < PP; ++p) {
    const float dx = ox - kx[p];
    const float dy = oy - ky[p];
    const float dz = oz - kz[p];
    const float d2 = dx * dx + dy * dy + dz * dz;
    if (d2 < 0.0025f) {          // w > 0  <=>  sqrt(d2) < 0.05
      const float w = (1.0f - 20.0f * sqrtf(d2)) * invnum;
      const int slot = atomicAdd(&cnt[n], 1);
      if (slot < MAXH) {
        rec_key[(size_t)n * MAXH + slot] = id | (p << 16);
        rec_w[(size_t)n * MAXH + slot] = w;
      }
    }
  }
}

// Kernel 3: one wave per query, gather its hits, write output exactly once
// (coalesced float2 per lane). No memset, no atomics on out.
__global__ __launch_bounds__(256) void apply_kernel(
    const float* __restrict__ x, const float* __restrict__ weights,
    const int* __restrict__ cnt, const int* __restrict__ rec_key,
    const float* __restrict__ rec_w, float* __restrict__ out) {
  const int wave = threadIdx.x >> 6;
  const int lane = threadIdx.x & 63;
  const int n = blockIdx.x * 4 + wave;   // grid is exactly N_Q/4

  int c = cnt[n];                        // wave-uniform broadcast load
  if (c > MAXH) c = MAXH;

  float a0 = 0.f, a1 = 0.f;
  const int o = lane * 2;
  for (int s = 0; s < c; ++s) {          // wave-uniform trip count
    const int   key = rec_key[(size_t)n * MAXH + s];
    const float w   = rec_w[(size_t)n * MAXH + s];
    const int id = key & 0xFFFF;
    const int p  = key >> 16;
    const float xv = x[(size_t)id * IN_DIM + lane];   // coalesced 256B row
    const float* wp = weights + (size_t)p * IN_DIM * OUT_DIM + o;
    float h0 = 0.f, h1 = 0.f;
    #pragma unroll 16
    for (int d = 0; d < IN_DIM; ++d) {
      const float xd = __shfl(xv, d);                 // broadcast x[id][d]
      const float2 w2 = *reinterpret_cast<const float2*>(wp + (size_t)d * OUT_DIM);
      h0 += xd * w2.x;
      h1 += xd * w2.y;
    }
    a0 += w * h0;
    a1 += w * h1;
  }
  float2 r;
  r.x = a0;
  r.y = a1;
  *reinterpret_cast<float2*>(out + (size_t)n * OUT_DIM + o) = r;
}

extern "C" void kernel_launch(void* const* d_in, const int* in_sizes, int n_in,
                              void* d_out, int out_size, void* d_ws, size_t ws_size,
                              hipStream_t stream) {
  const float* q_pts   = (const float*)d_in[0];
  const float* s_pts   = (const float*)d_in[1];
  const int*   nidx    = (const int*)d_in[2];
  const float* x       = (const float*)d_in[3];
  const float* weights = (const float*)d_in[4];
  const float* kpts    = (const float*)d_in[5];
  float* out = (float*)d_out;

  char* ws = (char*)d_ws;
  int*   cnt     = (int*)(ws);
  int*   valid   = (int*)(ws + (512u << 10));
  int*   rec_key = (int*)(ws + (1u << 20));
  float* rec_w   = (float*)(ws + (16u << 20));

  rowsum_valid_kernel<<<(N_S * 16) / 256, 256, 0, stream>>>(x, valid, cnt);
  detect_kernel<<<(N_Q * KK) / 256, 256, 0, stream>>>(
      q_pts, s_pts, nidx, kpts, valid, cnt, rec_key, rec_w);
  apply_kernel<<<N_Q / 4, 256, 0, stream>>>(x, weights, cnt, rec_key, rec_w, out);
}

// Round 4
// 113.078 us; speedup vs baseline: 1.0845x; 1.0845x over previous
//
#include <hip/hip_runtime.h>

#define N_Q     40000
#define N_S     40000
#define KK      32
#define PP      15
#define IN_DIM  64
#define OUT_DIM 128

// Kernel 1: valid[s] = (sum_d x[s,d] > 0). 16 lanes per row, coalesced float4.
__global__ __launch_bounds__(256) void rowsum_valid_kernel(
    const float* __restrict__ x, int* __restrict__ valid) {
  int t = blockIdx.x * 256 + threadIdx.x;
  int row = t >> 4;   // 16 lanes per row
  int sub = t & 15;
  if (row >= N_S) return;
  float4 v = reinterpret_cast<const float4*>(x + (size_t)row * IN_DIM)[sub];
  float s = (v.x + v.y) + (v.z + v.w);
  s += __shfl_xor(s, 1, 64);
  s += __shfl_xor(s, 2, 64);
  s += __shfl_xor(s, 4, 64);
  s += __shfl_xor(s, 8, 64);
  if (sub == 0) valid[row] = (s > 0.0f) ? 1 : 0;
}

// Kernel 2 (fused): one thread per (query, neighbor). Lanes 0-31 = query A,
// lanes 32-63 = query B. Kernel points live in registers (unrolled p-loop).
// Rare hits are work-shared across the wave; accumulators are kept per query
// IN REGISTERS and each output row is written exactly once, coalesced.
// No LDS, no barriers, no atomics, no memset, no intermediate buffers.
__global__ __launch_bounds__(256) void kpconv_fused_kernel(
    const float* __restrict__ q_pts, const float* __restrict__ s_pts,
    const int* __restrict__ nidx, const float* __restrict__ x,
    const float* __restrict__ weights, const float* __restrict__ kpts,
    const int* __restrict__ valid, float* __restrict__ out) {
  const int tid  = blockIdx.x * 256 + threadIdx.x;
  const int lane = threadIdx.x & 63;
  const int n  = tid >> 5;            // this lane's query
  const int nA = (tid & ~63) >> 5;    // wave's first query (lanes 0-31)

  // 45 uniform floats -> SGPRs/VGPRs, one pipelined wait, no per-p reloads
  float kx[PP], ky[PP], kz[PP];
  #pragma unroll
  for (int p = 0; p < PP; ++p) {
    kx[p] = kpts[p * 3 + 0];
    ky[p] = kpts[p * 3 + 1];
    kz[p] = kpts[p * 3 + 2];
  }

  const int id = nidx[tid];           // coalesced
  const bool real = (id < N_S);       // id == N_S: shadow row (origin, zero feats)
  float ox = 0.f, oy = 0.f, oz = 0.f;
  int v = 0;
  if (real) {
    ox = s_pts[id * 3 + 0];
    oy = s_pts[id * 3 + 1];
    oz = s_pts[id * 3 + 2];
    v  = valid[id];
  }
  ox -= q_pts[n * 3 + 0];
  oy -= q_pts[n * 3 + 1];
  oz -= q_pts[n * 3 + 2];

  // neighbor_num per query: popcount of this half-wave's ballot
  unsigned long long bal = __ballot(v != 0);
  unsigned int half = (lane < 32) ? (unsigned int)bal
                                  : (unsigned int)(bal >> 32);
  int num = (int)__popc(half);
  if (num < 1) num = 1;
  const float invnum = 1.0f / (float)num;

  float a0 = 0.f, a1 = 0.f;   // query A: lane's output cols 2*lane, 2*lane+1
  float b0 = 0.f, b1 = 0.f;   // query B

  #pragma unroll
  for (int p = 0; p < PP; ++p) {
    const float dx = ox - kx[p];
    const float dy = oy - ky[p];
    const float dz = oz - kz[p];
    const float d2 = dx * dx + dy * dy + dz * dz;
    const bool hit = real && (d2 < 0.0025f);   // w>0 <=> sqrt(d2) < 0.05
    unsigned long long b2 = __ballot(hit);
    if (b2 != 0ull) {                           // rare, wave-uniform
      const float wn = hit ? (1.0f - 20.0f * sqrtf(d2)) * invnum : 0.0f;
      while (b2) {
        const int j = __ffsll(b2) - 1;
        b2 &= b2 - 1;
        const float wj  = __shfl(wn, j);
        const int   idj = __shfl(id, j);
        // whole wave computes x[idj] @ W[p]; lane owns 2 output columns
        const float xv = x[(size_t)idj * IN_DIM + lane];   // coalesced 256B
        const float* wp = weights + (size_t)p * IN_DIM * OUT_DIM + 2 * lane;
        float h0 = 0.f, h1 = 0.f;
        #pragma unroll 16
        for (int d = 0; d < IN_DIM; ++d) {
          const float xd = __shfl(xv, d);                  // broadcast
          const float2 w2 = *reinterpret_cast<const float2*>(wp + (size_t)d * OUT_DIM);
          h0 += xd * w2.x;
          h1 += xd * w2.y;
        }
        if (j < 32) { a0 += wj * h0; a1 += wj * h1; }      // wave-uniform branch
        else        { b0 += wj * h0; b1 += wj * h1; }
      }
    }
  }

  // Exactly-once coalesced output: wave writes its two 512B rows.
  float2 ra; ra.x = a0; ra.y = a1;
  float2 rb; rb.x = b0; rb.y = b1;
  *reinterpret_cast<float2*>(out + (size_t)nA * OUT_DIM + 2 * lane) = ra;
  *reinterpret_cast<float2*>(out + (size_t)(nA + 1) * OUT_DIM + 2 * lane) = rb;
}

extern "C" void kernel_launch(void* const* d_in, const int* in_sizes, int n_in,
                              void* d_out, int out_size, void* d_ws, size_t ws_size,
                              hipStream_t stream) {
  const float* q_pts   = (const float*)d_in[0];
  const float* s_pts   = (const float*)d_in[1];
  const int*   nidx    = (const int*)d_in[2];
  const float* x       = (const float*)d_in[3];
  const float* weights = (const float*)d_in[4];
  const float* kpts    = (const float*)d_in[5];
  float* out = (float*)d_out;
  int* valid = (int*)d_ws;   // N_S ints

  rowsum_valid_kernel<<<(N_S * 16) / 256, 256, 0, stream>>>(x, valid);
  kpconv_fused_kernel<<<(N_Q * KK) / 256, 256, 0, stream>>>(
      q_pts, s_pts, nidx, x, weights, kpts, valid, out);
}

// Round 5
// 105.073 us; speedup vs baseline: 1.1671x; 1.0762x over previous
//
#include <hip/hip_runtime.h>
#include <hip/hip_bf16.h>

#define N_Q     40000
#define N_S     40000
#define KK      32
#define PP      15
#define IN_DIM  64
#define OUT_DIM 128

// ws layout:
//   packed : (N_S+1) float4 @ 0        (sx,sy,sz,validflag; last = shadow zeros)
//   wbf    : PP*IN_DIM*OUT_DIM bf16 @ 1 MiB  (W rounded to bf16)

// Kernel 1: blocks [0,2500): rowsum -> valid flag + packed float4 point table.
//           blocks [2500,2740): convert weights fp32 -> bf16 (2 elems/thread).
__global__ __launch_bounds__(256) void prep_kernel(
    const float* __restrict__ x, const float* __restrict__ s_pts,
    const float* __restrict__ weights,
    float4* __restrict__ packed, __hip_bfloat162* __restrict__ wbf) {
  const int b = blockIdx.x;
  if (b < 2500) {
    const int t = b * 256 + threadIdx.x;
    const int row = t >> 4;   // 16 lanes per row
    const int sub = t & 15;
    float4 v = reinterpret_cast<const float4*>(x + (size_t)row * IN_DIM)[sub];
    float s = (v.x + v.y) + (v.z + v.w);
    s += __shfl_xor(s, 1, 64);
    s += __shfl_xor(s, 2, 64);
    s += __shfl_xor(s, 4, 64);
    s += __shfl_xor(s, 8, 64);
    if (sub == 0) {
      float4 pkt;
      pkt.x = s_pts[row * 3 + 0];
      pkt.y = s_pts[row * 3 + 1];
      pkt.z = s_pts[row * 3 + 2];
      pkt.w = (s > 0.0f) ? 1.0f : 0.0f;
      packed[row] = pkt;
    }
    if (t == 1) {   // shadow support point: origin, invalid
      float4 z; z.x = 0.f; z.y = 0.f; z.z = 0.f; z.w = 0.f;
      packed[N_S] = z;
    }
  } else {
    const int t = (b - 2500) * 256 + threadIdx.x;   // 0..61439, 2 floats each
    float2 w2 = reinterpret_cast<const float2*>(weights)[t];
    __hip_bfloat162 h;
    h.x = __float2bfloat16(w2.x);
    h.y = __float2bfloat16(w2.y);
    wbf[t] = h;
  }
}

// Kernel 2 (fused): one thread per (query, neighbor). Lanes 0-31 = query A,
// lanes 32-63 = query B. ONE divergent 16B gather per thread (packed table),
// kernel points in registers, hits work-shared across the wave with x
// broadcast via uniform float4 loads (HW broadcast, no ds_bpermute) and W
// read as bf16 (half the L1 line traffic). Output written exactly once.
__global__ __launch_bounds__(256) void kpconv_fused_kernel(
    const float* __restrict__ q_pts, const int* __restrict__ nidx,
    const float* __restrict__ x, const float* __restrict__ kpts,
    const float4* __restrict__ packed, const __hip_bfloat162* __restrict__ wbf,
    float* __restrict__ out) {
  const int tid  = blockIdx.x * 256 + threadIdx.x;
  const int lane = threadIdx.x & 63;
  const int n  = tid >> 5;            // this lane's query
  const int nA = (tid & ~63) >> 5;    // wave's first query (lanes 0-31)

  // 45 uniform floats; uniform base + constant offsets -> scalar loads
  float kx[PP], ky[PP], kz[PP];
  #pragma unroll
  for (int p = 0; p < PP; ++p) {
    kx[p] = kpts[p * 3 + 0];
    ky[p] = kpts[p * 3 + 1];
    kz[p] = kpts[p * 3 + 2];
  }

  const int id = nidx[tid];           // coalesced; id in [0, N_S]
  const float4 sp = packed[id];       // ONE divergent 16B load
  const bool real = (id < N_S);

  const float ox = sp.x - q_pts[n * 3 + 0];
  const float oy = sp.y - q_pts[n * 3 + 1];
  const float oz = sp.z - q_pts[n * 3 + 2];

  // neighbor_num per query: popcount of this half-wave's ballot
  unsigned long long bal = __ballot(sp.w != 0.0f);
  unsigned int half = (lane < 32) ? (unsigned int)bal
                                  : (unsigned int)(bal >> 32);
  int num = (int)__popc(half);
  if (num < 1) num = 1;
  const float invnum = 1.0f / (float)num;

  float a0 = 0.f, a1 = 0.f;   // query A: output cols 2*lane, 2*lane+1
  float b0 = 0.f, b1 = 0.f;   // query B

  #pragma unroll
  for (int p = 0; p < PP; ++p) {
    const float dx = ox - kx[p];
    const float dy = oy - ky[p];
    const float dz = oz - kz[p];
    const float d2 = dx * dx + dy * dy + dz * dz;
    const bool hit = real && (d2 < 0.0025f);   // w>0 <=> sqrt(d2) < 0.05
    unsigned long long b2 = __ballot(hit);
    if (b2 != 0ull) {                           // rare, wave-uniform
      const float wn = hit ? (1.0f - 20.0f * sqrtf(d2)) * invnum : 0.0f;
      while (b2) {
        const int j = __ffsll(b2) - 1;
        b2 &= b2 - 1;
        const float wj  = __shfl(wn, j);
        const int   idj = __shfl(id, j);
        const float* xr = x + (size_t)idj * IN_DIM;
        const __hip_bfloat162* wp =
            wbf + (size_t)p * (IN_DIM * OUT_DIM / 2) + lane;
        float h0 = 0.f, h1 = 0.f;
        #pragma unroll 4
        for (int d4 = 0; d4 < IN_DIM / 4; ++d4) {
          const float4 xv4 =
              *reinterpret_cast<const float4*>(xr + 4 * d4);  // uniform: HW bcast
          #pragma unroll
          for (int dd = 0; dd < 4; ++dd) {
            const int d = 4 * d4 + dd;
            const __hip_bfloat162 w2 = wp[(size_t)d * (OUT_DIM / 2)];
            const float xd = (dd == 0) ? xv4.x : (dd == 1) ? xv4.y
                           : (dd == 2) ? xv4.z : xv4.w;
            h0 += xd * __bfloat162float(w2.x);
            h1 += xd * __bfloat162float(w2.y);
          }
        }
        if (j < 32) { a0 += wj * h0; a1 += wj * h1; }   // wave-uniform branch
        else        { b0 += wj * h0; b1 += wj * h1; }
      }
    }
  }

  // Exactly-once coalesced output: wave writes its two 512B rows.
  float2 ra; ra.x = a0; ra.y = a1;
  float2 rb; rb.x = b0; rb.y = b1;
  *reinterpret_cast<float2*>(out + (size_t)nA * OUT_DIM + 2 * lane) = ra;
  *reinterpret_cast<float2*>(out + (size_t)(nA + 1) * OUT_DIM + 2 * lane) = rb;
}

extern "C" void kernel_launch(void* const* d_in, const int* in_sizes, int n_in,
                              void* d_out, int out_size, void* d_ws, size_t ws_size,
                              hipStream_t stream) {
  const float* q_pts   = (const float*)d_in[0];
  const float* s_pts   = (const float*)d_in[1];
  const int*   nidx    = (const int*)d_in[2];
  const float* x       = (const float*)d_in[3];
  const float* weights = (const float*)d_in[4];
  const float* kpts    = (const float*)d_in[5];
  float* out = (float*)d_out;

  char* ws = (char*)d_ws;
  float4*          packed = (float4*)ws;                 // (N_S+1)*16 B = 640 KB
  __hip_bfloat162* wbf    = (__hip_bfloat162*)(ws + (1u << 20));  // 240 KB

  prep_kernel<<<2740, 256, 0, stream>>>(x, s_pts, weights, packed, wbf);
  kpconv_fused_kernel<<<(N_Q * KK) / 256, 256, 0, stream>>>(
      q_pts, nidx, x, kpts, packed, wbf, out);
}

// Round 6
// 99.784 us; speedup vs baseline: 1.2290x; 1.0530x over previous
//
#include <hip/hip_runtime.h>

#define N_Q     40000
#define N_S     40000
#define KK      32
#define PP      15
#define IN_DIM  64
#define OUT_DIM 128

typedef __attribute__((ext_vector_type(8))) short short8;   // 8 bf16 (A/B frag)
typedef __attribute__((ext_vector_type(4))) float floatx4;  // mfma C/D frag

// float -> bf16 bits, round-to-nearest-even
static __device__ __forceinline__ short f2bf(float f) {
  union { float f; unsigned u; } v; v.f = f;
  unsigned r = v.u + 0x7FFFu + ((v.u >> 16) & 1u);
  return (short)(r >> 16);
}

// ws layout:
//   packed : (N_S+1) float4 @ 0      (sx,sy,sz,valid; last entry = shadow zeros)
//   wmf    : 240 KB @ 1 MiB          (W as bf16, pre-swizzled into mfma B-frags:
//            frag fi=(p*8+g)*2+kc holds B[n=lane&15][k=kc*32+quad*8+j] = W[p][k][g*16+n])

// Kernel 1: blocks [0,2500): rowsum -> valid flag + packed float4 point table.
//           blocks [2500,2740): swizzle W fp32 -> bf16 mfma B-fragment layout.
__global__ __launch_bounds__(256) void prep_kernel(
    const float* __restrict__ x, const float* __restrict__ s_pts,
    const float* __restrict__ weights,
    float4* __restrict__ packed, unsigned* __restrict__ wmf) {
  const int b = blockIdx.x;
  if (b < 2500) {
    const int t = b * 256 + threadIdx.x;
    const int row = t >> 4;   // 16 lanes per row
    const int sub = t & 15;
    float4 v = reinterpret_cast<const float4*>(x + (size_t)row * IN_DIM)[sub];
    float s = (v.x + v.y) + (v.z + v.w);
    s += __shfl_xor(s, 1, 64);
    s += __shfl_xor(s, 2, 64);
    s += __shfl_xor(s, 4, 64);
    s += __shfl_xor(s, 8, 64);
    if (sub == 0) {
      float4 pkt;
      pkt.x = s_pts[row * 3 + 0];
      pkt.y = s_pts[row * 3 + 1];
      pkt.z = s_pts[row * 3 + 2];
      pkt.w = (s > 0.0f) ? 1.0f : 0.0f;
      packed[row] = pkt;
    }
    if (t == 1) {   // shadow support point: origin, invalid
      float4 z; z.x = 0.f; z.y = 0.f; z.z = 0.f; z.w = 0.f;
      packed[N_S] = z;
    }
  } else {
    // one uint (2 bf16, consecutive k) per thread; flat index t matches
    // uint4 index fi*64+lane used by the consumer (t = fi*256 + lane*4 + j2)
    const int t = (b - 2500) * 256 + threadIdx.x;   // 0..61439
    const int j2   = t & 3;
    const int lane = (t >> 2) & 63;
    const int fi   = t >> 8;            // (p*8+g)*2+kc, 0..239
    const int kc = fi & 1, g = (fi >> 1) & 7, p = fi >> 4;
    const int c  = g * 16 + (lane & 15);
    const int k0 = kc * 32 + (lane >> 4) * 8 + 2 * j2;
    const float w0 = weights[(size_t)p * (IN_DIM * OUT_DIM) + (size_t)k0 * OUT_DIM + c];
    const float w1 = weights[(size_t)p * (IN_DIM * OUT_DIM) + (size_t)(k0 + 1) * OUT_DIM + c];
    wmf[t] = (unsigned)(unsigned short)f2bf(w0)
           | ((unsigned)(unsigned short)f2bf(w1) << 16);
  }
}

// Kernel 2 (fused): one thread per (query, neighbor); lanes 0-31 = query A,
// 32-63 = query B. Lane l (<15) owns kernel point l in registers. Per thread:
// one ball early-out test; candidates (~3/wave) are processed wave-cooperatively
// (lanes 0-14 evaluate all 15 distances at once); each rare hit runs 16 MFMAs
// (rows 0/1 = queries A/B) against the pre-swizzled bf16 W. Output written
// exactly once by lanes 0-15 from the mfma accumulators.
__global__ __launch_bounds__(256, 4) void kpconv_fused_kernel(
    const float* __restrict__ q_pts, const int* __restrict__ nidx,
    const float* __restrict__ x, const float* __restrict__ kpts,
    const float4* __restrict__ packed, const uint4* __restrict__ wmf4,
    float* __restrict__ out) {
  const int tid  = blockIdx.x * 256 + threadIdx.x;
  const int lane = threadIdx.x & 63;
  const int n  = tid >> 5;            // this lane's query
  const int nA = (tid & ~63) >> 5;    // wave's first query

  // lane-resident kernel point (lanes >=15 duplicate point 0)
  const int pl = (lane < PP) ? lane : 0;
  const float kxl = kpts[pl * 3 + 0];
  const float kyl = kpts[pl * 3 + 1];
  const float kzl = kpts[pl * 3 + 2];

  // candidate radius: R = max_p |kp| + KP_EXTENT
  float r2 = kxl * kxl + kyl * kyl + kzl * kzl;
  #pragma unroll
  for (int s = 32; s; s >>= 1) r2 = fmaxf(r2, __shfl_xor(r2, s, 64));
  const float R  = sqrtf(r2) + 0.05f;
  const float R2 = R * R;

  const int id = nidx[tid];           // coalesced; id in [0, N_S]
  const float4 sp = packed[id];       // ONE divergent 16B gather
  const bool real = (id < N_S);

  const float ox = sp.x - q_pts[n * 3 + 0];
  const float oy = sp.y - q_pts[n * 3 + 1];
  const float oz = sp.z - q_pts[n * 3 + 2];

  // neighbor_num per query (shadow entry has sp.w == 0)
  unsigned long long bal = __ballot(sp.w != 0.0f);
  unsigned int half = (lane < 32) ? (unsigned int)bal
                                  : (unsigned int)(bal >> 32);
  int num = (int)__popc(half);
  if (num < 1) num = 1;
  const float invnum = 1.0f / (float)num;

  floatx4 acc[8];
  #pragma unroll
  for (int g = 0; g < 8; ++g) acc[g] = (floatx4){0.f, 0.f, 0.f, 0.f};

  const float d2o = ox * ox + oy * oy + oz * oz;
  unsigned long long bc = __ballot(real && (d2o <= R2));
  while (bc) {
    const int j = (int)__ffsll((unsigned long long)bc) - 1;
    bc &= bc - 1;
    const float oxj = __shfl(ox, j);
    const float oyj = __shfl(oy, j);
    const float ozj = __shfl(oz, j);
    const int   idj = __shfl(id, j);
    const float inj = __shfl(invnum, j);
    // lanes 0-14 evaluate all 15 kernel points for candidate j in parallel
    const float dx = oxj - kxl, dy = oyj - kyl, dz = ozj - kzl;
    const float d2 = dx * dx + dy * dy + dz * dz;
    const bool hit = (lane < PP) && (d2 < 0.0025f);
    const float wc = hit ? (1.0f - 20.0f * sqrtf(d2)) * inj : 0.0f;
    unsigned long long bh = __ballot(hit);
    const int m = j >> 5;   // 0: query A, 1: query B
    while (bh) {
      const int h = (int)__ffsll((unsigned long long)bh) - 1;
      bh &= bh - 1;
      const float wj = __shfl(wc, h);
      const int p = h;
      // A fragments (rows: m only): A[m][k=quad*8+e(+32)] = wj * x[idj][k]
      short8 af0 = {0, 0, 0, 0, 0, 0, 0, 0};
      short8 af1 = {0, 0, 0, 0, 0, 0, 0, 0};
      if ((lane & 15) == m) {
        const float4* xr = reinterpret_cast<const float4*>(x + (size_t)idj * IN_DIM);
        const int q4 = (lane >> 4) * 2;
        const float4 xa = xr[q4],     xb = xr[q4 + 1];   // k-chunk 0
        const float4 xc = xr[q4 + 8], xd = xr[q4 + 9];   // k-chunk 1
        af0[0] = f2bf(wj * xa.x); af0[1] = f2bf(wj * xa.y);
        af0[2] = f2bf(wj * xa.z); af0[3] = f2bf(wj * xa.w);
        af0[4] = f2bf(wj * xb.x); af0[5] = f2bf(wj * xb.y);
        af0[6] = f2bf(wj * xb.z); af0[7] = f2bf(wj * xb.w);
        af1[0] = f2bf(wj * xc.x); af1[1] = f2bf(wj * xc.y);
        af1[2] = f2bf(wj * xc.z); af1[3] = f2bf(wj * xc.w);
        af1[4] = f2bf(wj * xd.x); af1[5] = f2bf(wj * xd.y);
        af1[6] = f2bf(wj * xd.z); af1[7] = f2bf(wj * xd.w);
      }
      #pragma unroll
      for (int g = 0; g < 8; ++g) {
        const uint4 b0 = wmf4[(size_t)((p * 8 + g) * 2 + 0) * 64 + lane];
        acc[g] = __builtin_amdgcn_mfma_f32_16x16x32_bf16(
            af0, __builtin_bit_cast(short8, b0), acc[g], 0, 0, 0);
        const uint4 b1 = wmf4[(size_t)((p * 8 + g) * 2 + 1) * 64 + lane];
        acc[g] = __builtin_amdgcn_mfma_f32_16x16x32_bf16(
            af1, __builtin_bit_cast(short8, b1), acc[g], 0, 0, 0);
      }
    }
  }

  // D layout: col = lane&15, row = (lane>>4)*4 + reg -> rows 0/1 live in
  // lanes 0-15, regs 0/1. Zero-hit queries write zeros (correct: 0/num).
  if (lane < 16) {
    #pragma unroll
    for (int g = 0; g < 8; ++g) {
      out[(size_t)nA * OUT_DIM + g * 16 + lane]       = acc[g][0];
      out[(size_t)(nA + 1) * OUT_DIM + g * 16 + lane] = acc[g][1];
    }
  }
}

extern "C" void kernel_launch(void* const* d_in, const int* in_sizes, int n_in,
                              void* d_out, int out_size, void* d_ws, size_t ws_size,
                              hipStream_t stream) {
  const float* q_pts   = (const float*)d_in[0];
  const float* s_pts   = (const float*)d_in[1];
  const int*   nidx    = (const int*)d_in[2];
  const float* x       = (const float*)d_in[3];
  const float* weights = (const float*)d_in[4];
  const float* kpts    = (const float*)d_in[5];
  float* out = (float*)d_out;

  char* ws = (char*)d_ws;
  float4*   packed = (float4*)ws;                     // (N_S+1)*16 B = 640 KB
  unsigned* wmf    = (unsigned*)(ws + (1u << 20));    // 240 KB, mfma B-frag order

  prep_kernel<<<2740, 256, 0, stream>>>(x, s_pts, weights, packed, wmf);
  kpconv_fused_kernel<<<(N_Q * KK) / 256, 256, 0, stream>>>(
      q_pts, nidx, x, kpts, packed, (const uint4*)wmf, out);
}